// Round 14
// baseline (10045.580 us; speedup 1.0000x reference)
//
#include <hip/hip_runtime.h>
#include <math.h>

#define B_SZ 8
#define NP   2048
#define KNN  20
#define CNT_F 327680.0f   // B*N*K

// ---------------- ws layout (BYTE offsets) ----------------
#define OB_LOC   0ull            // f32 16384*512 = 33,554,432
#define OB_RB    33554432ull     // 41,943,040: S strip | ybuf | z1
#define OB_RC    75497472ull     // 16,777,216: y5 | z2
#define OB_RD    92274688ull     //  8,388,608: emb
#define OB_X0    100663296ull    //    262,144: x0 f32 (b,n,4)
#define OB_XX    100925440ull    //     65,536
#define OB_STD   100990976ull    //  1,310,720 topk dist state | psum2 (slab phase)
#define OB_STI   102301696ull    //  1,310,720 topk idx state (final knn idx)
#define OB_MEAN  103613440ull    //        128
#define OB_VAR   103613568ull    //        128
#define OB_GLB   103613696ull    //     16,384
#define OB_T1    103630080ull    //     16,384
#define OB_GM    103646464ull    //      1,024
#define OB_GR    103647488ull    //      1,024
// end = 103,648,512 B

// ---------------- prep: (B,3,N) -> (b,n,4) fp32 exact ----------------
__global__ __launch_bounds__(256) void k_prep(const float* __restrict__ xin, float* __restrict__ x0) {
    int t = blockIdx.x * 256 + threadIdx.x;
    if (t >= B_SZ * NP) return;
    int b = t >> 11, n = t & 2047;
    const float* s = xin + (size_t)b * 3 * NP + n;
    ((float4*)x0)[t] = make_float4(s[0], s[NP], s[2 * NP], 0.f);
}

// ---------------- xx = np.sum(x*x, axis=1): c-sequential, rounded squares, no FMA ----------------
template <int C>
__global__ __launch_bounds__(256) void k_xx(const float* __restrict__ x, int rs, float* __restrict__ xx) {
    int t = blockIdx.x * 256 + threadIdx.x;
    if (t >= B_SZ * NP) return;
    const float* p = x + (size_t)t * rs;
    float s = 0.f;
    for (int c = 0; c < C; ++c) s = __fadd_rn(s, __fmul_rn(p[c], p[c]));
    xx[t] = s;
}

// ---------------- pd strip GEMM (np-fp32 bit-exact): S[row, 512-strip] ----------------
template <int KT>
__global__ __launch_bounds__(256) void k_pds(const float* __restrict__ x, int rs,
                                             const float* __restrict__ xx, int j0,
                                             float* __restrict__ S) {
    constexpr int KS = (KT < 16) ? KT : 16;
    __shared__ float Xs[KS][68];
    __shared__ float Ws[KS][132];
    int b = blockIdx.z;
    int m0 = blockIdx.x * 64, o0 = blockIdx.y * 128;
    const float* xb = x + (size_t)b * NP * rs;
    const float* xcb = xb + (size_t)(j0 + o0) * rs;
    int tid = threadIdx.x;
    int tx = tid & 15, ty = tid >> 4;
    float acc[4][8] = {};
    for (int k0 = 0; k0 < KT; k0 += KS) {
        __syncthreads();
        for (int e = tid; e < KS * 64; e += 256) {
            int kk = e % KS, mm = e / KS;
            Xs[kk][mm] = xb[(size_t)(m0 + mm) * rs + k0 + kk];
        }
        for (int e = tid; e < KS * 128; e += 256) {
            int kk = e % KS, oo = e / KS;
            Ws[kk][oo] = xcb[(size_t)oo * rs + k0 + kk];
        }
        __syncthreads();
#pragma unroll
        for (int kk = 0; kk < KS; ++kk) {
            float4 a4 = *(const float4*)&Xs[kk][ty * 4];
            float4 b0 = *(const float4*)&Ws[kk][tx * 8];
            float4 b1 = *(const float4*)&Ws[kk][tx * 8 + 4];
            float av[4] = {a4.x, a4.y, a4.z, a4.w};
            float bv[8] = {b0.x, b0.y, b0.z, b0.w, b1.x, b1.y, b1.z, b1.w};
#pragma unroll
            for (int i = 0; i < 4; ++i)
#pragma unroll
                for (int j = 0; j < 8; ++j)
                    acc[i][j] = __fadd_rn(acc[i][j], __fmul_rn(av[i], bv[j]));
        }
    }
    const float* xxb = xx + b * NP;
#pragma unroll
    for (int i = 0; i < 4; ++i) {
        int m = m0 + ty * 4 + i;
        float nxx = -xxb[m];
        float* Sr = S + ((size_t)(b * NP + m)) * 512;
#pragma unroll
        for (int j = 0; j < 8; ++j) {
            int o = o0 + tx * 8 + j;
            float t2 = __fadd_rn(nxx, __fmul_rn(2.0f, acc[i][j]));
            Sr[o] = __fsub_rn(t2, xxb[j0 + o]);
        }
    }
}

// ---------------- streaming stable top-20 insert ----------------
__device__ __forceinline__ void tk_insert(float (&kd)[KNN], int (&ki)[KNN], float d, int j) {
    if (d <= kd[KNN - 1]) return;
#pragma unroll
    for (int t = 0; t < KNN; ++t) {
        if (d > kd[t]) { float td = kd[t]; kd[t] = d; d = td; int tj = ki[t]; ki[t] = j; j = tj; }
    }
}

// ---------------- top-20 over a 512-col strip: 8 rows/block x 32 lanes/row ----------------
__global__ __launch_bounds__(256) void k_topk(const float* __restrict__ S, float* __restrict__ std_,
                                              int* __restrict__ sti, int j0) {
    int tid = threadIdx.x;
    int row = blockIdx.x * 8 + (tid >> 5);
    int sub = tid & 31;
    float kd[KNN]; int ki[KNN];
#pragma unroll
    for (int t = 0; t < KNN; ++t) { kd[t] = -INFINITY; ki[t] = 0x7fffffff; }
    if (j0 != 0) {
        for (int t = sub; t < KNN; t += 32)
            tk_insert(kd, ki, std_[(size_t)row * KNN + t], sti[(size_t)row * KNN + t]);
    }
    const float* Sr = S + (size_t)row * 512;
    for (int q0 = sub * 4; q0 < 512; q0 += 128) {
        float4 d4 = *(const float4*)&Sr[q0];
        tk_insert(kd, ki, d4.x, j0 + q0 + 0);
        tk_insert(kd, ki, d4.y, j0 + q0 + 1);
        tk_insert(kd, ki, d4.z, j0 + q0 + 2);
        tk_insert(kd, ki, d4.w, j0 + q0 + 3);
    }
    for (int it = 0; it < KNN; ++it) {
        float v = kd[0]; int vi = ki[0];
#pragma unroll
        for (int m = 1; m < 32; m <<= 1) {
            float ov = __shfl_xor(v, m, 32);
            int ovi = __shfl_xor(vi, m, 32);
            if (ov > v || (ov == v && ovi < vi)) { v = ov; vi = ovi; }
        }
        if (sub == 0) { std_[(size_t)row * KNN + it] = v; sti[(size_t)row * KNN + it] = vi; }
        if (kd[0] == v && ki[0] == vi) {
#pragma unroll
            for (int t = 0; t < KNN - 1; ++t) { kd[t] = kd[t + 1]; ki[t] = ki[t + 1]; }
            kd[KNN - 1] = -INFINITY; ki[KNN - 1] = 0x7fffffff;
        }
    }
}

// ---------------- y = einsum SOP over e = [fl(xj-xn), xn]: c-seq, mul/add separately rounded ----------------
// Round-12 structure; ONLY change: float4 LDS reads (same c-ascending per-accumulator chain).
template <int C>
__global__ __launch_bounds__(256) void k_ymk(const float* __restrict__ x, int rs,
                                             const float* __restrict__ Wsl,
                                             const int* __restrict__ sti,
                                             float* __restrict__ ybuf) {
    constexpr int TC = 2 * C + ((C % 4 == 0) ? 4 : 1);
    constexpr int CP = (C % 4 == 0) ? C + 4 : C + 1;
    constexpr int XNP = (C + 3) & ~3;
    __shared__ __align__(16) float Ws[32][TC];
    __shared__ __align__(16) float Xd[KNN][CP];
    __shared__ __align__(16) float Xn[XNP];
    __shared__ int   sidx[KNN];
    int n = blockIdx.x, b = blockIdx.y;
    int tid = threadIdx.x;
    if (tid < KNN) sidx[tid] = sti[((size_t)b * NP + n) * KNN + tid];
    for (int e = tid; e < 32 * 2 * C; e += 256) {
        int o = e / (2 * C), c = e % (2 * C);
        Ws[o][c] = Wsl[(size_t)o * 2 * C + c];
    }
    if (tid < C) Xn[tid] = x[((size_t)b * NP + n) * rs + tid];
    __syncthreads();
    for (int e = tid; e < KNN * C; e += 256) {
        int k = e / C, c = e % C;
        Xd[k][c] = __fsub_rn(x[((size_t)b * NP + sidx[k]) * rs + c], Xn[c]);
    }
    __syncthreads();
    int o = tid & 31;
    int kb = tid >> 5;
    int k0 = kb, k1 = kb + 8, k2 = kb + 16;
    int k2r = (k2 < KNN) ? k2 : 0;
    float a0 = 0.f, a1 = 0.f, a2 = 0.f;
    if constexpr (C % 4 == 0) {
        for (int c = 0; c < C; c += 4) {
            float4 w = *(const float4*)&Ws[o][c];
            float4 d0 = *(const float4*)&Xd[k0][c];
            float4 d1 = *(const float4*)&Xd[k1][c];
            float4 d2 = *(const float4*)&Xd[k2r][c];
            a0 = __fadd_rn(a0, __fmul_rn(w.x, d0.x));
            a1 = __fadd_rn(a1, __fmul_rn(w.x, d1.x));
            a2 = __fadd_rn(a2, __fmul_rn(w.x, d2.x));
            a0 = __fadd_rn(a0, __fmul_rn(w.y, d0.y));
            a1 = __fadd_rn(a1, __fmul_rn(w.y, d1.y));
            a2 = __fadd_rn(a2, __fmul_rn(w.y, d2.y));
            a0 = __fadd_rn(a0, __fmul_rn(w.z, d0.z));
            a1 = __fadd_rn(a1, __fmul_rn(w.z, d1.z));
            a2 = __fadd_rn(a2, __fmul_rn(w.z, d2.z));
            a0 = __fadd_rn(a0, __fmul_rn(w.w, d0.w));
            a1 = __fadd_rn(a1, __fmul_rn(w.w, d1.w));
            a2 = __fadd_rn(a2, __fmul_rn(w.w, d2.w));
        }
        for (int c = 0; c < C; c += 4) {
            float4 w = *(const float4*)&Ws[o][C + c];
            float4 xn = *(const float4*)&Xn[c];
            float p0 = __fmul_rn(w.x, xn.x);
            a0 = __fadd_rn(a0, p0); a1 = __fadd_rn(a1, p0); a2 = __fadd_rn(a2, p0);
            float p1 = __fmul_rn(w.y, xn.y);
            a0 = __fadd_rn(a0, p1); a1 = __fadd_rn(a1, p1); a2 = __fadd_rn(a2, p1);
            float p2 = __fmul_rn(w.z, xn.z);
            a0 = __fadd_rn(a0, p2); a1 = __fadd_rn(a1, p2); a2 = __fadd_rn(a2, p2);
            float p3 = __fmul_rn(w.w, xn.w);
            a0 = __fadd_rn(a0, p3); a1 = __fadd_rn(a1, p3); a2 = __fadd_rn(a2, p3);
        }
    } else {
        for (int c = 0; c < C; ++c) {
            float w = Ws[o][c];
            a0 = __fadd_rn(a0, __fmul_rn(w, Xd[k0][c]));
            a1 = __fadd_rn(a1, __fmul_rn(w, Xd[k1][c]));
            a2 = __fadd_rn(a2, __fmul_rn(w, Xd[k2r][c]));
        }
        for (int c = 0; c < C; ++c) {
            float p = __fmul_rn(Ws[o][C + c], Xn[c]);
            a0 = __fadd_rn(a0, p);
            a1 = __fadd_rn(a1, p);
            a2 = __fadd_rn(a2, p);
        }
    }
    size_t base = ((size_t)(b * 32 + o) * NP + n) * KNN;
    ybuf[base + k0] = a0;
    ybuf[base + k1] = a1;
    if (k2 < KNN) ybuf[base + k2] = a2;
}

// ---------------- numpy pairwise_sum: 4 blocks/task, 16 node-sums each ----------------
__global__ __launch_bounds__(256) void k_pwsum(const float* __restrict__ ybuf,
                                               const float* __restrict__ meanv, int vmode,
                                               float* __restrict__ psum2) {
    __shared__ float ns[16];
    int tid = threadIdx.x;
    int blk = blockIdx.x;              // 0..1023
    int task = blk >> 2;               // b*32+o
    int part = blk & 3;
    int o = task & 31;
    float m = vmode ? meanv[o] : 0.f;
    int wave = tid >> 6, lane = tid & 63;
    int leafj = lane >> 3, slot = lane & 7;
    const float* tb = ybuf + (size_t)task * (NP * KNN) + (size_t)part * 16 * 640;
    for (int itg = 0; itg < 4; ++itg) {
        int g = itg * 4 + wave;
        const float* a = tb + g * 640 + leafj * 80 + slot;
        float v0 = a[0];
        if (vmode) { float t = __fsub_rn(v0, m); v0 = __fmul_rn(t, t); }
        float r = v0;
#pragma unroll
        for (int i = 1; i < 10; ++i) {
            float v = a[i * 8];
            if (vmode) { float t = __fsub_rn(v, m); v = __fmul_rn(t, t); }
            r = __fadd_rn(r, v);
        }
#pragma unroll
        for (int msk = 1; msk < 64; msk <<= 1)
            r = __fadd_rn(r, __shfl_xor(r, msk));
        if (lane == 0) ns[g] = r;
    }
    __syncthreads();
    if (tid < 16) {
        float v = ns[tid];
#pragma unroll
        for (int msk = 1; msk < 16; msk <<= 1)
            v = __fadd_rn(v, __shfl_xor(v, msk, 16));
        if (tid == 0) psum2[blk] = v;
    }
}

__global__ __launch_bounds__(64) void k_comb(const float* __restrict__ psum2, float* __restrict__ outv) {
    int o = threadIdx.x;
    if (o >= 32) return;
    float tot = 0.f;
    for (int b = 0; b < B_SZ; ++b) {
        const float* p = psum2 + (size_t)(b * 32 + o) * 4;
        float q = __fadd_rn(__fadd_rn(p[0], p[1]), __fadd_rn(p[2], p[3]));
        tot = (b == 0) ? q : __fadd_rn(tot, q);
    }
    outv[o] = __fdiv_rn(tot, CNT_F);
}

// ---------------- max_k -> BN affine -> lrelu -> loc (np elementwise order) ----------------
__global__ __launch_bounds__(256) void k_xwrite(const float* __restrict__ ybuf,
                                                const float* __restrict__ meanv, const float* __restrict__ varv,
                                                const float* __restrict__ g, const float* __restrict__ bb,
                                                int coff, float* __restrict__ loc) {
    int t = blockIdx.x * 256 + threadIdx.x;   // (b, o, n)
    int n = t & 2047;
    int o = (t >> 11) & 31;
    int b = t >> 16;
    if (b >= B_SZ) return;
    const float* yr = ybuf + ((size_t)(b * 32 + o) * NP + n) * KNN;
    float gv = g[o];
    float sel = yr[0];
    if (gv >= 0.f) { for (int k = 1; k < KNN; ++k) sel = fmaxf(sel, yr[k]); }
    else           { for (int k = 1; k < KNN; ++k) sel = fminf(sel, yr[k]); }
    float s = __fsqrt_rn(__fadd_rn(varv[o], 1e-5f));
    float d = __fdiv_rn(__fsub_rn(sel, meanv[o]), s);
    float z = __fadd_rn(__fmul_rn(d, gv), bb[o]);
    z = (z >= 0.f) ? z : __fmul_rn(0.2f, z);
    loc[((size_t)b * NP + n) * 512 + coff + o] = z;
}

// ---------------- stage C/D (approximate fp32; smooth) ----------------
__global__ __launch_bounds__(256) void enc_gemm(
    const float* __restrict__ X, long long bsX, int rsX,
    const float* __restrict__ W, int rsW, int K, int O,
    float* __restrict__ out, long long bsO, int rsO,
    const float* __restrict__ aux, long long bsA, int mode) {
    __shared__ float Xs[16][132];
    __shared__ float Ws[16][132];
    int b = blockIdx.z;
    int m0 = blockIdx.x * 128, o0 = blockIdx.y * 128;
    const float* Xb = X + (size_t)b * bsX;
    int tid = threadIdx.x;
    int tx = tid & 15, ty = tid >> 4;
    float acc[8][8] = {};
    for (int k0 = 0; k0 < K; k0 += 16) {
        __syncthreads();
#pragma unroll
        for (int i = 0; i < 8; ++i) {
            int e = tid + i * 256;
            int kk = e & 15, mm = e >> 4;
            int k = k0 + kk;
            Xs[kk][mm] = (k < K) ? Xb[(size_t)(m0 + mm) * rsX + k] : 0.f;
        }
#pragma unroll
        for (int i = 0; i < 8; ++i) {
            int e = tid + i * 256;
            int kk = e & 15, oo = e >> 4;
            int k = k0 + kk, o = o0 + oo;
            Ws[kk][oo] = (k < K && o < O) ? W[(size_t)o * rsW + k] : 0.f;
        }
        __syncthreads();
#pragma unroll
        for (int kk = 0; kk < 16; ++kk) {
            float4 a0 = *(const float4*)&Xs[kk][ty * 8];
            float4 a1 = *(const float4*)&Xs[kk][ty * 8 + 4];
            float4 b0 = *(const float4*)&Ws[kk][tx * 8];
            float4 b1 = *(const float4*)&Ws[kk][tx * 8 + 4];
            float av[8] = {a0.x, a0.y, a0.z, a0.w, a1.x, a1.y, a1.z, a1.w};
            float bv[8] = {b0.x, b0.y, b0.z, b0.w, b1.x, b1.y, b1.z, b1.w};
#pragma unroll
            for (int i = 0; i < 8; ++i)
#pragma unroll
                for (int j = 0; j < 8; ++j)
                    acc[i][j] += av[i] * bv[j];
        }
    }
    float* ob = out + (size_t)b * bsO;
    const float* ax = aux ? aux + (size_t)b * bsA : nullptr;
#pragma unroll
    for (int i = 0; i < 8; ++i) {
        int m = m0 + ty * 8 + i;
#pragma unroll
        for (int j = 0; j < 8; ++j) {
            int o = o0 + tx * 8 + j;
            if (o < O) {
                float val = acc[i][j];
                if (mode == 1) val += ax[o];
                ob[(size_t)m * rsO + o] = val;
            }
        }
    }
}

__global__ __launch_bounds__(256) void enc_gn5(const float* __restrict__ y, const float* __restrict__ g5,
                                               const float* __restrict__ b5, float* __restrict__ glb) {
    int b = blockIdx.y, g = blockIdx.x;
    int tid = threadIdx.x;
    const float* yb = y + (size_t)b * NP * 256 + g * 8;
    float s1 = 0.f, s2 = 0.f;
    for (int e = tid; e < NP * 8; e += 256) {
        int n = e >> 3, c = e & 7;
        float x = yb[(size_t)n * 256 + c];
        s1 += x; s2 += x * x;
    }
    __shared__ float rbuf[16];
#pragma unroll
    for (int m = 32; m >= 1; m >>= 1) { s1 += __shfl_xor(s1, m, 64); s2 += __shfl_xor(s2, m, 64); }
    if ((tid & 63) == 0) { rbuf[tid >> 6] = s1; rbuf[8 + (tid >> 6)] = s2; }
    __syncthreads();
    float S1 = rbuf[0] + rbuf[1] + rbuf[2] + rbuf[3];
    float S2 = rbuf[8] + rbuf[9] + rbuf[10] + rbuf[11];
    float mean = S1 / (float)(NP * 8);
    float var = S2 / (float)(NP * 8) - mean * mean;
    float rstd = rsqrtf(var + 1e-5f);
    int c = tid & 7;
    float gam = g5[g * 8 + c], bet = b5[g * 8 + c];
    float mx = -INFINITY, sum = 0.f;
    for (int e = tid; e < NP * 8; e += 256) {
        int n = e >> 3;
        float x = yb[(size_t)n * 256 + c];
        float z = (x - mean) * rstd * gam + bet;
        z = (z >= 0.f) ? z : 0.2f * z;
        mx = fmaxf(mx, z); sum += z;
    }
    __shared__ float smx[256], ssm[256];
    smx[tid] = mx; ssm[tid] = sum;
    __syncthreads();
    if (tid < 8) {
        float M = -INFINITY, S = 0.f;
        for (int i = tid; i < 256; i += 8) { M = fmaxf(M, smx[i]); S += ssm[i]; }
        glb[b * 512 + g * 8 + tid] = M;
        glb[b * 512 + 256 + g * 8 + tid] = S / (float)NP;
    }
}

__global__ __launch_bounds__(128) void enc_t1(const float* __restrict__ Wm1, const float* __restrict__ bm1,
                                              const float* __restrict__ glb, float* __restrict__ t1) {
    int b = blockIdx.y;
    int o = blockIdx.x * 128 + threadIdx.x;
    __shared__ float sg[512];
    for (int i = threadIdx.x; i < 512; i += 128) sg[i] = glb[b * 512 + i];
    __syncthreads();
    const float* wr = Wm1 + (size_t)o * 1024 + 512;
    float s = bm1[o];
    for (int c = 0; c < 512; ++c) s += wr[c] * sg[c];
    t1[b * 512 + o] = s;
}

__global__ __launch_bounds__(256) void enc_gnstats(const float* __restrict__ y, int C, int cgshift,
                                                   float* __restrict__ gmean, float* __restrict__ grstd) {
    int b = blockIdx.y, g = blockIdx.x;
    int Cg = 1 << cgshift;
    int tid = threadIdx.x;
    const float* yb = y + (size_t)b * NP * C + g * Cg;
    int tot = NP << cgshift;
    float s1 = 0.f, s2 = 0.f;
    for (int e = tid; e < tot; e += 256) {
        int n = e >> cgshift, c = e & (Cg - 1);
        float x = yb[(size_t)n * C + c];
        s1 += x; s2 += x * x;
    }
    __shared__ float rbuf[16];
#pragma unroll
    for (int m = 32; m >= 1; m >>= 1) { s1 += __shfl_xor(s1, m, 64); s2 += __shfl_xor(s2, m, 64); }
    if ((tid & 63) == 0) { rbuf[tid >> 6] = s1; rbuf[8 + (tid >> 6)] = s2; }
    __syncthreads();
    if (tid == 0) {
        float S1 = rbuf[0] + rbuf[1] + rbuf[2] + rbuf[3];
        float S2 = rbuf[8] + rbuf[9] + rbuf[10] + rbuf[11];
        float mean = S1 / (float)tot;
        float var = S2 / (float)tot - mean * mean;
        gmean[b * 32 + g] = mean;
        grstd[b * 32 + g] = rsqrtf(var + 1e-5f);
    }
}

__global__ __launch_bounds__(256) void enc_gnapply(float* __restrict__ y, int C, int cgshift, int bshift,
                                                   const float* __restrict__ gam, const float* __restrict__ bet,
                                                   const float* __restrict__ gmean, const float* __restrict__ grstd) {
    int t = blockIdx.x * 256 + threadIdx.x;
    if (t >= B_SZ * NP * C) return;
    int c = t & (C - 1);
    int b = t >> bshift;
    int g = c >> cgshift;
    float m = gmean[b * 32 + g], r = grstd[b * 32 + g];
    float z = (y[t] - m) * r * gam[c] + bet[c];
    y[t] = (z >= 0.f) ? z : 0.f;
}

__global__ void enc_out(const float* __restrict__ emb, float* __restrict__ out) {
    __shared__ float tile[32][33];
    int b = blockIdx.z;
    int n0 = blockIdx.x * 32, c0 = blockIdx.y * 32;
    int tx = threadIdx.x, ty = threadIdx.y;
    for (int i = ty; i < 32; i += 8)
        tile[i][tx] = emb[((size_t)b * NP + n0 + i) * 128 + c0 + tx];
    __syncthreads();
    for (int i = ty; i < 32; i += 8)
        out[((size_t)b * 128 + c0 + i) * NP + n0 + tx] = tile[tx][i];
}

__global__ __launch_bounds__(256) void enc_outglb(const float* __restrict__ glb, float* __restrict__ out) {
    int t = blockIdx.x * 256 + threadIdx.x;
    if (t < B_SZ * 512) out[2097152 + t] = glb[t];
}

// ---------------- host launch ----------------
extern "C" void kernel_launch(void* const* d_in, const int* in_sizes, int n_in,
                              void* d_out, int out_size, void* d_ws, size_t ws_size,
                              hipStream_t stream) {
    (void)in_sizes; (void)n_in; (void)out_size; (void)ws_size;
    const float* xin = (const float*)d_in[0];
    const float* W1 = (const float*)d_in[1];  const float* g1 = (const float*)d_in[2];  const float* b1 = (const float*)d_in[3];
    const float* W2 = (const float*)d_in[4];  const float* g2 = (const float*)d_in[5];  const float* b2 = (const float*)d_in[6];
    const float* W3 = (const float*)d_in[7];  const float* g3 = (const float*)d_in[8];  const float* b3 = (const float*)d_in[9];
    const float* W4 = (const float*)d_in[10]; const float* g4 = (const float*)d_in[11]; const float* b4 = (const float*)d_in[12];
    const float* W5 = (const float*)d_in[13]; const float* g5 = (const float*)d_in[14]; const float* b5 = (const float*)d_in[15];
    const float* Wm1 = (const float*)d_in[16]; const float* bm1 = (const float*)d_in[17];
    const float* gm1 = (const float*)d_in[18]; const float* hm1 = (const float*)d_in[19];
    const float* Wm2 = (const float*)d_in[20]; const float* bm2 = (const float*)d_in[21];
    const float* gm2 = (const float*)d_in[22]; const float* hm2 = (const float*)d_in[23];
    const float* Wm3 = (const float*)d_in[24]; const float* bm3 = (const float*)d_in[25];
    const float* gm3 = (const float*)d_in[26]; const float* hm3 = (const float*)d_in[27];
    float* out = (float*)d_out;
    char* base = (char*)d_ws;

    float* loc    = (float*)(base + OB_LOC);
    float* S      = (float*)(base + OB_RB);
    float* ybuf   = (float*)(base + OB_RB);
    float* z1     = (float*)(base + OB_RB);
    float* y5     = (float*)(base + OB_RC);
    float* z2     = (float*)(base + OB_RC);
    float* emb    = (float*)(base + OB_RD);
    float* x0     = (float*)(base + OB_X0);
    float* xx     = (float*)(base + OB_XX);
    float* std_   = (float*)(base + OB_STD);
    float* psum2  = (float*)(base + OB_STD);   // std_ dead during slab phase
    int*   sti    = (int*)  (base + OB_STI);
    float* meanv  = (float*)(base + OB_MEAN);
    float* varv   = (float*)(base + OB_VAR);
    float* glb    = (float*)(base + OB_GLB);
    float* t1     = (float*)(base + OB_T1);
    float* gm     = (float*)(base + OB_GM);
    float* gr     = (float*)(base + OB_GR);

    k_prep<<<64, 256, 0, stream>>>(xin, x0);

    struct LY { const float* x; int rs; int C; const float* W; int O;
                const float* g; const float* bb; int coff; };
    LY L[4] = {
        {x0,        4,   3,   W1, 64,  g1, b1, 0},
        {loc,       512, 64,  W2, 64,  g2, b2, 64},
        {loc + 64,  512, 64,  W3, 128, g3, b3, 128},
        {loc + 128, 512, 128, W4, 256, g4, b4, 256},
    };

    for (int l = 0; l < 4; ++l) {
        const LY& e = L[l];
        // --- kNN ranking: pd strip GEMM + stable top-20 ---
        if (e.C == 3)       k_xx<3><<<64, 256, 0, stream>>>(e.x, e.rs, xx);
        else if (e.C == 64) k_xx<64><<<64, 256, 0, stream>>>(e.x, e.rs, xx);
        else                k_xx<128><<<64, 256, 0, stream>>>(e.x, e.rs, xx);
        dim3 gp(32, 4, B_SZ);
        for (int s = 0; s < 4; ++s) {
            if (e.C == 3)       k_pds<4><<<gp, 256, 0, stream>>>(e.x, e.rs, xx, s * 512, S);
            else if (e.C == 64) k_pds<64><<<gp, 256, 0, stream>>>(e.x, e.rs, xx, s * 512, S);
            else                k_pds<128><<<gp, 256, 0, stream>>>(e.x, e.rs, xx, s * 512, S);
            k_topk<<<2048, 256, 0, stream>>>(S, std_, sti, s * 512);
        }
        // --- edge conv + BN + lrelu + max, slab of 32 channels (np-fp32 exact) ---
        for (int o0 = 0; o0 < e.O; o0 += 32) {
            const float* Wsl = e.W + (size_t)o0 * 2 * e.C;
            dim3 gym(NP, B_SZ);
            if (e.C == 3)       k_ymk<3><<<gym, 256, 0, stream>>>(e.x, e.rs, Wsl, sti, ybuf);
            else if (e.C == 64) k_ymk<64><<<gym, 256, 0, stream>>>(e.x, e.rs, Wsl, sti, ybuf);
            else                k_ymk<128><<<gym, 256, 0, stream>>>(e.x, e.rs, Wsl, sti, ybuf);
            k_pwsum<<<1024, 256, 0, stream>>>(ybuf, nullptr, 0, psum2);
            k_comb<<<1, 64, 0, stream>>>(psum2, meanv);
            k_pwsum<<<1024, 256, 0, stream>>>(ybuf, meanv, 1, psum2);
            k_comb<<<1, 64, 0, stream>>>(psum2, varv);
            k_xwrite<<<2048, 256, 0, stream>>>(ybuf, meanv, varv,
                                               e.g + o0, e.bb + o0, e.coff + o0, loc);
        }
    }

    auto gemm = [&](const float* X, int rsX, const float* Wp, int rsW, int K, int O,
                    float* o_, int rsO, const float* aux, long long bsA, int mode) {
        dim3 g(NP / 128, (O + 127) / 128, B_SZ);
        enc_gemm<<<g, 256, 0, stream>>>(X, (long long)NP * rsX, rsX, Wp, rsW, K, O,
                                        o_, (long long)NP * rsO, rsO, aux, bsA, mode);
    };

    // stage C
    gemm(loc, 512, W5, 512, 512, 256, y5, 256, nullptr, 0, 0);
    enc_gn5<<<dim3(32, B_SZ), 256, 0, stream>>>(y5, g5, b5, glb);
    enc_t1<<<dim3(4, B_SZ), 128, 0, stream>>>(Wm1, bm1, glb, t1);

    // stage D
    gemm(loc, 512, Wm1, 1024, 512, 512, z1, 512, t1, 512, 1);
    enc_gnstats<<<dim3(32, B_SZ), 256, 0, stream>>>(z1, 512, 4, gm, gr);
    enc_gnapply<<<(B_SZ * NP * 512) / 256, 256, 0, stream>>>(z1, 512, 4, 20, gm1, hm1, gm, gr);

    gemm(z1, 512, Wm2, 512, 512, 256, z2, 256, bm2, 0, 1);
    enc_gnstats<<<dim3(32, B_SZ), 256, 0, stream>>>(z2, 256, 3, gm, gr);
    enc_gnapply<<<(B_SZ * NP * 256) / 256, 256, 0, stream>>>(z2, 256, 3, 19, gm2, hm2, gm, gr);

    gemm(z2, 256, Wm3, 256, 256, 128, emb, 128, bm3, 0, 1);
    enc_gnstats<<<dim3(32, B_SZ), 256, 0, stream>>>(emb, 128, 2, gm, gr);
    enc_gnapply<<<(B_SZ * NP * 128) / 256, 256, 0, stream>>>(emb, 128, 2, 18, gm3, hm3, gm, gr);

    enc_out<<<dim3(64, 4, B_SZ), dim3(32, 8), 0, stream>>>(emb, out);
    enc_outglb<<<16, 256, 0, stream>>>(glb, out);
}

// Round 15
// 7726.350 us; speedup vs baseline: 1.3002x; 1.3002x over previous
//
#include <hip/hip_runtime.h>
#include <math.h>

#define B_SZ 8
#define NP   2048
#define KNN  20
#define CNT_F 327680.0f   // B*N*K

// ---------------- ws layout (BYTE offsets) ----------------
#define OB_LOC   0ull            // f32 16384*512 = 33,554,432
#define OB_RB    33554432ull     // 41,943,040: S strip | ybuf | z1
#define OB_RC    75497472ull     // 16,777,216: y5 | z2
#define OB_RD    92274688ull     //  8,388,608: emb
#define OB_X0    100663296ull    //    262,144: x0 f32 (b,n,4)
#define OB_XX    100925440ull    //     65,536
#define OB_STD   100990976ull    //  1,310,720 topk dist state | psum2m/psum2v (slab phase)
#define OB_STI   102301696ull    //  1,310,720 topk idx state (final knn idx)
#define OB_GLB   103613696ull    //     16,384
#define OB_T1    103630080ull    //     16,384
#define OB_GM    103646464ull    //      1,024
#define OB_GR    103647488ull    //      1,024
// end = 103,648,512 B

// ---------------- prep: (B,3,N) -> (b,n,4) fp32 exact ----------------
__global__ __launch_bounds__(256) void k_prep(const float* __restrict__ xin, float* __restrict__ x0) {
    int t = blockIdx.x * 256 + threadIdx.x;
    if (t >= B_SZ * NP) return;
    int b = t >> 11, n = t & 2047;
    const float* s = xin + (size_t)b * 3 * NP + n;
    ((float4*)x0)[t] = make_float4(s[0], s[NP], s[2 * NP], 0.f);
}

// ---------------- xx = np.sum(x*x, axis=1): c-sequential, rounded squares, no FMA ----------------
template <int C>
__global__ __launch_bounds__(256) void k_xx(const float* __restrict__ x, int rs, float* __restrict__ xx) {
    int t = blockIdx.x * 256 + threadIdx.x;
    if (t >= B_SZ * NP) return;
    const float* p = x + (size_t)t * rs;
    float s = 0.f;
    for (int c = 0; c < C; ++c) s = __fadd_rn(s, __fmul_rn(p[c], p[c]));
    xx[t] = s;
}

// ---------------- pd strip GEMM (np-fp32 bit-exact): S[row, 512-strip] ----------------
template <int KT>
__global__ __launch_bounds__(256) void k_pds(const float* __restrict__ x, int rs,
                                             const float* __restrict__ xx, int j0,
                                             float* __restrict__ S) {
    constexpr int KS = (KT < 16) ? KT : 16;
    __shared__ float Xs[KS][68];
    __shared__ float Ws[KS][132];
    int b = blockIdx.z;
    int m0 = blockIdx.x * 64, o0 = blockIdx.y * 128;
    const float* xb = x + (size_t)b * NP * rs;
    const float* xcb = xb + (size_t)(j0 + o0) * rs;
    int tid = threadIdx.x;
    int tx = tid & 15, ty = tid >> 4;
    float acc[4][8] = {};
    for (int k0 = 0; k0 < KT; k0 += KS) {
        __syncthreads();
        for (int e = tid; e < KS * 64; e += 256) {
            int kk = e % KS, mm = e / KS;
            Xs[kk][mm] = xb[(size_t)(m0 + mm) * rs + k0 + kk];
        }
        for (int e = tid; e < KS * 128; e += 256) {
            int kk = e % KS, oo = e / KS;
            Ws[kk][oo] = xcb[(size_t)oo * rs + k0 + kk];
        }
        __syncthreads();
#pragma unroll
        for (int kk = 0; kk < KS; ++kk) {
            float4 a4 = *(const float4*)&Xs[kk][ty * 4];
            float4 b0 = *(const float4*)&Ws[kk][tx * 8];
            float4 b1 = *(const float4*)&Ws[kk][tx * 8 + 4];
            float av[4] = {a4.x, a4.y, a4.z, a4.w};
            float bv[8] = {b0.x, b0.y, b0.z, b0.w, b1.x, b1.y, b1.z, b1.w};
#pragma unroll
            for (int i = 0; i < 4; ++i)
#pragma unroll
                for (int j = 0; j < 8; ++j)
                    acc[i][j] = __fadd_rn(acc[i][j], __fmul_rn(av[i], bv[j]));
        }
    }
    const float* xxb = xx + b * NP;
#pragma unroll
    for (int i = 0; i < 4; ++i) {
        int m = m0 + ty * 4 + i;
        float nxx = -xxb[m];
        float* Sr = S + ((size_t)(b * NP + m)) * 512;
#pragma unroll
        for (int j = 0; j < 8; ++j) {
            int o = o0 + tx * 8 + j;
            float t2 = __fadd_rn(nxx, __fmul_rn(2.0f, acc[i][j]));
            Sr[o] = __fsub_rn(t2, xxb[j0 + o]);
        }
    }
}

// ---------------- streaming stable top-20 insert ----------------
__device__ __forceinline__ void tk_insert(float (&kd)[KNN], int (&ki)[KNN], float d, int j) {
    if (d <= kd[KNN - 1]) return;
#pragma unroll
    for (int t = 0; t < KNN; ++t) {
        if (d > kd[t]) { float td = kd[t]; kd[t] = d; d = td; int tj = ki[t]; ki[t] = j; j = tj; }
    }
}

// ---------------- top-20 over a 512-col strip: 8 rows/block x 32 lanes/row ----------------
__global__ __launch_bounds__(256) void k_topk(const float* __restrict__ S, float* __restrict__ std_,
                                              int* __restrict__ sti, int j0) {
    int tid = threadIdx.x;
    int row = blockIdx.x * 8 + (tid >> 5);
    int sub = tid & 31;
    float kd[KNN]; int ki[KNN];
#pragma unroll
    for (int t = 0; t < KNN; ++t) { kd[t] = -INFINITY; ki[t] = 0x7fffffff; }
    if (j0 != 0) {
        for (int t = sub; t < KNN; t += 32)
            tk_insert(kd, ki, std_[(size_t)row * KNN + t], sti[(size_t)row * KNN + t]);
    }
    const float* Sr = S + (size_t)row * 512;
    for (int q0 = sub * 4; q0 < 512; q0 += 128) {
        float4 d4 = *(const float4*)&Sr[q0];
        tk_insert(kd, ki, d4.x, j0 + q0 + 0);
        tk_insert(kd, ki, d4.y, j0 + q0 + 1);
        tk_insert(kd, ki, d4.z, j0 + q0 + 2);
        tk_insert(kd, ki, d4.w, j0 + q0 + 3);
    }
    for (int it = 0; it < KNN; ++it) {
        float v = kd[0]; int vi = ki[0];
#pragma unroll
        for (int m = 1; m < 32; m <<= 1) {
            float ov = __shfl_xor(v, m, 32);
            int ovi = __shfl_xor(vi, m, 32);
            if (ov > v || (ov == v && ovi < vi)) { v = ov; vi = ovi; }
        }
        if (sub == 0) { std_[(size_t)row * KNN + it] = v; sti[(size_t)row * KNN + it] = vi; }
        if (kd[0] == v && ki[0] == vi) {
#pragma unroll
            for (int t = 0; t < KNN - 1; ++t) { kd[t] = kd[t + 1]; ki[t] = ki[t + 1]; }
            kd[KNN - 1] = -INFINITY; ki[KNN - 1] = 0x7fffffff;
        }
    }
}

// ---------------- y = einsum SOP over e = [fl(xj-xn), xn]: c-seq, mul/add separately rounded ----------------
// Round-12 scalar form verbatim (proven bit-exact, VGPR 68).
template <int C>
__global__ __launch_bounds__(256) void k_ymk(const float* __restrict__ x, int rs,
                                             const float* __restrict__ Wsl,
                                             const int* __restrict__ sti,
                                             float* __restrict__ ybuf) {
    __shared__ float Ws[32][2 * C + 1];
    __shared__ float Xd[KNN][C + 1];
    __shared__ float Xn[C];
    __shared__ int   sidx[KNN];
    int n = blockIdx.x, b = blockIdx.y;
    int tid = threadIdx.x;
    if (tid < KNN) sidx[tid] = sti[((size_t)b * NP + n) * KNN + tid];
    for (int e = tid; e < 32 * 2 * C; e += 256) {
        int o = e / (2 * C), c = e % (2 * C);
        Ws[o][c] = Wsl[(size_t)o * 2 * C + c];
    }
    if (tid < C) Xn[tid] = x[((size_t)b * NP + n) * rs + tid];
    __syncthreads();
    for (int e = tid; e < KNN * C; e += 256) {
        int k = e / C, c = e % C;
        Xd[k][c] = __fsub_rn(x[((size_t)b * NP + sidx[k]) * rs + c], Xn[c]);
    }
    __syncthreads();
    int o = tid & 31;
    int kb = tid >> 5;
    int k0 = kb, k1 = kb + 8, k2 = kb + 16;
    int k2r = (k2 < KNN) ? k2 : 0;
    float a0 = 0.f, a1 = 0.f, a2 = 0.f;
    for (int c = 0; c < C; ++c) {
        float w = Ws[o][c];
        a0 = __fadd_rn(a0, __fmul_rn(w, Xd[k0][c]));
        a1 = __fadd_rn(a1, __fmul_rn(w, Xd[k1][c]));
        a2 = __fadd_rn(a2, __fmul_rn(w, Xd[k2r][c]));
    }
    for (int c = 0; c < C; ++c) {
        float p = __fmul_rn(Ws[o][C + c], Xn[c]);
        a0 = __fadd_rn(a0, p);
        a1 = __fadd_rn(a1, p);
        a2 = __fadd_rn(a2, p);
    }
    size_t base = ((size_t)(b * 32 + o) * NP + n) * KNN;
    ybuf[base + k0] = a0;
    ybuf[base + k1] = a1;
    if (k2 < KNN) ybuf[base + k2] = a2;
}

// ---------------- combine helper: ((p0+p1)+(p2+p3)) chained over b, /count ----------------
// Bit-identical to the former k_comb sequence.
__device__ __forceinline__ float pw_combine(const float* __restrict__ p2, int o) {
    float tot = 0.f;
    for (int b = 0; b < B_SZ; ++b) {
        const float* p = p2 + (size_t)(b * 32 + o) * 4;
        float q = __fadd_rn(__fadd_rn(p[0], p[1]), __fadd_rn(p[2], p[3]));
        tot = (b == 0) ? q : __fadd_rn(tot, q);
    }
    return __fdiv_rn(tot, CNT_F);
}

// ---------------- numpy pairwise_sum: 4 blocks/task, 16 node-sums each ----------------
// vmode=1: mean combined inline from psum2m (replaces k_comb launch).
__global__ __launch_bounds__(256) void k_pwsum(const float* __restrict__ ybuf,
                                               const float* __restrict__ psum2m, int vmode,
                                               float* __restrict__ psum2out) {
    __shared__ float ns[16];
    int tid = threadIdx.x;
    int blk = blockIdx.x;              // 0..1023
    int task = blk >> 2;               // b*32+o
    int part = blk & 3;
    int o = task & 31;
    float m = vmode ? pw_combine(psum2m, o) : 0.f;
    int wave = tid >> 6, lane = tid & 63;
    int leafj = lane >> 3, slot = lane & 7;
    const float* tb = ybuf + (size_t)task * (NP * KNN) + (size_t)part * 16 * 640;
    for (int itg = 0; itg < 4; ++itg) {
        int g = itg * 4 + wave;
        const float* a = tb + g * 640 + leafj * 80 + slot;
        float v0 = a[0];
        if (vmode) { float t = __fsub_rn(v0, m); v0 = __fmul_rn(t, t); }
        float r = v0;
#pragma unroll
        for (int i = 1; i < 10; ++i) {
            float v = a[i * 8];
            if (vmode) { float t = __fsub_rn(v, m); v = __fmul_rn(t, t); }
            r = __fadd_rn(r, v);
        }
#pragma unroll
        for (int msk = 1; msk < 64; msk <<= 1)
            r = __fadd_rn(r, __shfl_xor(r, msk));
        if (lane == 0) ns[g] = r;
    }
    __syncthreads();
    if (tid < 16) {
        float v = ns[tid];
#pragma unroll
        for (int msk = 1; msk < 16; msk <<= 1)
            v = __fadd_rn(v, __shfl_xor(v, msk, 16));
        if (tid == 0) psum2out[blk] = v;
    }
}

// ---------------- max_k -> BN affine -> lrelu -> loc; mean/var combined inline ----------------
__global__ __launch_bounds__(256) void k_xwrite(const float* __restrict__ ybuf,
                                                const float* __restrict__ psum2m, const float* __restrict__ psum2v,
                                                const float* __restrict__ g, const float* __restrict__ bb,
                                                int coff, float* __restrict__ loc) {
    int t = blockIdx.x * 256 + threadIdx.x;   // (b, o, n)
    int n = t & 2047;
    int o = (t >> 11) & 31;
    int b = t >> 16;
    if (b >= B_SZ) return;
    float mean = pw_combine(psum2m, o);
    float var  = pw_combine(psum2v, o);
    const float* yr = ybuf + ((size_t)(b * 32 + o) * NP + n) * KNN;
    float gv = g[o];
    float sel = yr[0];
    if (gv >= 0.f) { for (int k = 1; k < KNN; ++k) sel = fmaxf(sel, yr[k]); }
    else           { for (int k = 1; k < KNN; ++k) sel = fminf(sel, yr[k]); }
    float s = __fsqrt_rn(__fadd_rn(var, 1e-5f));
    float d = __fdiv_rn(__fsub_rn(sel, mean), s);
    float z = __fadd_rn(__fmul_rn(d, gv), bb[o]);
    z = (z >= 0.f) ? z : __fmul_rn(0.2f, z);
    loc[((size_t)b * NP + n) * 512 + coff + o] = z;
}

// ---------------- stage C/D (approximate fp32; smooth) ----------------
__global__ __launch_bounds__(256) void enc_gemm(
    const float* __restrict__ X, long long bsX, int rsX,
    const float* __restrict__ W, int rsW, int K, int O,
    float* __restrict__ out, long long bsO, int rsO,
    const float* __restrict__ aux, long long bsA, int mode) {
    __shared__ float Xs[16][132];
    __shared__ float Ws[16][132];
    int b = blockIdx.z;
    int m0 = blockIdx.x * 128, o0 = blockIdx.y * 128;
    const float* Xb = X + (size_t)b * bsX;
    int tid = threadIdx.x;
    int tx = tid & 15, ty = tid >> 4;
    float acc[8][8] = {};
    for (int k0 = 0; k0 < K; k0 += 16) {
        __syncthreads();
#pragma unroll
        for (int i = 0; i < 8; ++i) {
            int e = tid + i * 256;
            int kk = e & 15, mm = e >> 4;
            int k = k0 + kk;
            Xs[kk][mm] = (k < K) ? Xb[(size_t)(m0 + mm) * rsX + k] : 0.f;
        }
#pragma unroll
        for (int i = 0; i < 8; ++i) {
            int e = tid + i * 256;
            int kk = e & 15, oo = e >> 4;
            int k = k0 + kk, o = o0 + oo;
            Ws[kk][oo] = (k < K && o < O) ? W[(size_t)o * rsW + k] : 0.f;
        }
        __syncthreads();
#pragma unroll
        for (int kk = 0; kk < 16; ++kk) {
            float4 a0 = *(const float4*)&Xs[kk][ty * 8];
            float4 a1 = *(const float4*)&Xs[kk][ty * 8 + 4];
            float4 b0 = *(const float4*)&Ws[kk][tx * 8];
            float4 b1 = *(const float4*)&Ws[kk][tx * 8 + 4];
            float av[8] = {a0.x, a0.y, a0.z, a0.w, a1.x, a1.y, a1.z, a1.w};
            float bv[8] = {b0.x, b0.y, b0.z, b0.w, b1.x, b1.y, b1.z, b1.w};
#pragma unroll
            for (int i = 0; i < 8; ++i)
#pragma unroll
                for (int j = 0; j < 8; ++j)
                    acc[i][j] += av[i] * bv[j];
        }
    }
    float* ob = out + (size_t)b * bsO;
    const float* ax = aux ? aux + (size_t)b * bsA : nullptr;
#pragma unroll
    for (int i = 0; i < 8; ++i) {
        int m = m0 + ty * 8 + i;
#pragma unroll
        for (int j = 0; j < 8; ++j) {
            int o = o0 + tx * 8 + j;
            if (o < O) {
                float val = acc[i][j];
                if (mode == 1) val += ax[o];
                ob[(size_t)m * rsO + o] = val;
            }
        }
    }
}

__global__ __launch_bounds__(256) void enc_gn5(const float* __restrict__ y, const float* __restrict__ g5,
                                               const float* __restrict__ b5, float* __restrict__ glb) {
    int b = blockIdx.y, g = blockIdx.x;
    int tid = threadIdx.x;
    const float* yb = y + (size_t)b * NP * 256 + g * 8;
    float s1 = 0.f, s2 = 0.f;
    for (int e = tid; e < NP * 8; e += 256) {
        int n = e >> 3, c = e & 7;
        float x = yb[(size_t)n * 256 + c];
        s1 += x; s2 += x * x;
    }
    __shared__ float rbuf[16];
#pragma unroll
    for (int m = 32; m >= 1; m >>= 1) { s1 += __shfl_xor(s1, m, 64); s2 += __shfl_xor(s2, m, 64); }
    if ((tid & 63) == 0) { rbuf[tid >> 6] = s1; rbuf[8 + (tid >> 6)] = s2; }
    __syncthreads();
    float S1 = rbuf[0] + rbuf[1] + rbuf[2] + rbuf[3];
    float S2 = rbuf[8] + rbuf[9] + rbuf[10] + rbuf[11];
    float mean = S1 / (float)(NP * 8);
    float var = S2 / (float)(NP * 8) - mean * mean;
    float rstd = rsqrtf(var + 1e-5f);
    int c = tid & 7;
    float gam = g5[g * 8 + c], bet = b5[g * 8 + c];
    float mx = -INFINITY, sum = 0.f;
    for (int e = tid; e < NP * 8; e += 256) {
        int n = e >> 3;
        float x = yb[(size_t)n * 256 + c];
        float z = (x - mean) * rstd * gam + bet;
        z = (z >= 0.f) ? z : 0.2f * z;
        mx = fmaxf(mx, z); sum += z;
    }
    __shared__ float smx[256], ssm[256];
    smx[tid] = mx; ssm[tid] = sum;
    __syncthreads();
    if (tid < 8) {
        float M = -INFINITY, S = 0.f;
        for (int i = tid; i < 256; i += 8) { M = fmaxf(M, smx[i]); S += ssm[i]; }
        glb[b * 512 + g * 8 + tid] = M;
        glb[b * 512 + 256 + g * 8 + tid] = S / (float)NP;
    }
}

__global__ __launch_bounds__(128) void enc_t1(const float* __restrict__ Wm1, const float* __restrict__ bm1,
                                              const float* __restrict__ glb, float* __restrict__ t1) {
    int b = blockIdx.y;
    int o = blockIdx.x * 128 + threadIdx.x;
    __shared__ float sg[512];
    for (int i = threadIdx.x; i < 512; i += 128) sg[i] = glb[b * 512 + i];
    __syncthreads();
    const float* wr = Wm1 + (size_t)o * 1024 + 512;
    float s = bm1[o];
    for (int c = 0; c < 512; ++c) s += wr[c] * sg[c];
    t1[b * 512 + o] = s;
}

__global__ __launch_bounds__(256) void enc_gnstats(const float* __restrict__ y, int C, int cgshift,
                                                   float* __restrict__ gmean, float* __restrict__ grstd) {
    int b = blockIdx.y, g = blockIdx.x;
    int Cg = 1 << cgshift;
    int tid = threadIdx.x;
    const float* yb = y + (size_t)b * NP * C + g * Cg;
    int tot = NP << cgshift;
    float s1 = 0.f, s2 = 0.f;
    for (int e = tid; e < tot; e += 256) {
        int n = e >> cgshift, c = e & (Cg - 1);
        float x = yb[(size_t)n * C + c];
        s1 += x; s2 += x * x;
    }
    __shared__ float rbuf[16];
#pragma unroll
    for (int m = 32; m >= 1; m >>= 1) { s1 += __shfl_xor(s1, m, 64); s2 += __shfl_xor(s2, m, 64); }
    if ((tid & 63) == 0) { rbuf[tid >> 6] = s1; rbuf[8 + (tid >> 6)] = s2; }
    __syncthreads();
    if (tid == 0) {
        float S1 = rbuf[0] + rbuf[1] + rbuf[2] + rbuf[3];
        float S2 = rbuf[8] + rbuf[9] + rbuf[10] + rbuf[11];
        float mean = S1 / (float)tot;
        float var = S2 / (float)tot - mean * mean;
        gmean[b * 32 + g] = mean;
        grstd[b * 32 + g] = rsqrtf(var + 1e-5f);
    }
}

__global__ __launch_bounds__(256) void enc_gnapply(float* __restrict__ y, int C, int cgshift, int bshift,
                                                   const float* __restrict__ gam, const float* __restrict__ bet,
                                                   const float* __restrict__ gmean, const float* __restrict__ grstd) {
    int t = blockIdx.x * 256 + threadIdx.x;
    if (t >= B_SZ * NP * C) return;
    int c = t & (C - 1);
    int b = t >> bshift;
    int g = c >> cgshift;
    float m = gmean[b * 32 + g], r = grstd[b * 32 + g];
    float z = (y[t] - m) * r * gam[c] + bet[c];
    y[t] = (z >= 0.f) ? z : 0.f;
}

__global__ void enc_out(const float* __restrict__ emb, float* __restrict__ out) {
    __shared__ float tile[32][33];
    int b = blockIdx.z;
    int n0 = blockIdx.x * 32, c0 = blockIdx.y * 32;
    int tx = threadIdx.x, ty = threadIdx.y;
    for (int i = ty; i < 32; i += 8)
        tile[i][tx] = emb[((size_t)b * NP + n0 + i) * 128 + c0 + tx];
    __syncthreads();
    for (int i = ty; i < 32; i += 8)
        out[((size_t)b * 128 + c0 + i) * NP + n0 + tx] = tile[tx][i];
}

__global__ __launch_bounds__(256) void enc_outglb(const float* __restrict__ glb, float* __restrict__ out) {
    int t = blockIdx.x * 256 + threadIdx.x;
    if (t < B_SZ * 512) out[2097152 + t] = glb[t];
}

// ---------------- host launch ----------------
extern "C" void kernel_launch(void* const* d_in, const int* in_sizes, int n_in,
                              void* d_out, int out_size, void* d_ws, size_t ws_size,
                              hipStream_t stream) {
    (void)in_sizes; (void)n_in; (void)out_size; (void)ws_size;
    const float* xin = (const float*)d_in[0];
    const float* W1 = (const float*)d_in[1];  const float* g1 = (const float*)d_in[2];  const float* b1 = (const float*)d_in[3];
    const float* W2 = (const float*)d_in[4];  const float* g2 = (const float*)d_in[5];  const float* b2 = (const float*)d_in[6];
    const float* W3 = (const float*)d_in[7];  const float* g3 = (const float*)d_in[8];  const float* b3 = (const float*)d_in[9];
    const float* W4 = (const float*)d_in[10]; const float* g4 = (const float*)d_in[11]; const float* b4 = (const float*)d_in[12];
    const float* W5 = (const float*)d_in[13]; const float* g5 = (const float*)d_in[14]; const float* b5 = (const float*)d_in[15];
    const float* Wm1 = (const float*)d_in[16]; const float* bm1 = (const float*)d_in[17];
    const float* gm1 = (const float*)d_in[18]; const float* hm1 = (const float*)d_in[19];
    const float* Wm2 = (const float*)d_in[20]; const float* bm2 = (const float*)d_in[21];
    const float* gm2 = (const float*)d_in[22]; const float* hm2 = (const float*)d_in[23];
    const float* Wm3 = (const float*)d_in[24]; const float* bm3 = (const float*)d_in[25];
    const float* gm3 = (const float*)d_in[26]; const float* hm3 = (const float*)d_in[27];
    float* out = (float*)d_out;
    char* base = (char*)d_ws;

    float* loc    = (float*)(base + OB_LOC);
    float* S      = (float*)(base + OB_RB);
    float* ybuf   = (float*)(base + OB_RB);
    float* z1     = (float*)(base + OB_RB);
    float* y5     = (float*)(base + OB_RC);
    float* z2     = (float*)(base + OB_RC);
    float* emb    = (float*)(base + OB_RD);
    float* x0     = (float*)(base + OB_X0);
    float* xx     = (float*)(base + OB_XX);
    float* std_   = (float*)(base + OB_STD);
    float* psum2m = (float*)(base + OB_STD);           // std_ dead during slab phase
    float* psum2v = (float*)(base + OB_STD + 8192);
    int*   sti    = (int*)  (base + OB_STI);
    float* glb    = (float*)(base + OB_GLB);
    float* t1     = (float*)(base + OB_T1);
    float* gm     = (float*)(base + OB_GM);
    float* gr     = (float*)(base + OB_GR);

    k_prep<<<64, 256, 0, stream>>>(xin, x0);

    struct LY { const float* x; int rs; int C; const float* W; int O;
                const float* g; const float* bb; int coff; };
    LY L[4] = {
        {x0,        4,   3,   W1, 64,  g1, b1, 0},
        {loc,       512, 64,  W2, 64,  g2, b2, 64},
        {loc + 64,  512, 64,  W3, 128, g3, b3, 128},
        {loc + 128, 512, 128, W4, 256, g4, b4, 256},
    };

    for (int l = 0; l < 4; ++l) {
        const LY& e = L[l];
        // --- kNN ranking: pd strip GEMM + stable top-20 ---
        if (e.C == 3)       k_xx<3><<<64, 256, 0, stream>>>(e.x, e.rs, xx);
        else if (e.C == 64) k_xx<64><<<64, 256, 0, stream>>>(e.x, e.rs, xx);
        else                k_xx<128><<<64, 256, 0, stream>>>(e.x, e.rs, xx);
        dim3 gp(32, 4, B_SZ);
        for (int s = 0; s < 4; ++s) {
            if (e.C == 3)       k_pds<4><<<gp, 256, 0, stream>>>(e.x, e.rs, xx, s * 512, S);
            else if (e.C == 64) k_pds<64><<<gp, 256, 0, stream>>>(e.x, e.rs, xx, s * 512, S);
            else                k_pds<128><<<gp, 256, 0, stream>>>(e.x, e.rs, xx, s * 512, S);
            k_topk<<<2048, 256, 0, stream>>>(S, std_, sti, s * 512);
        }
        // --- edge conv + BN + lrelu + max, slab of 32 channels (np-fp32 exact) ---
        for (int o0 = 0; o0 < e.O; o0 += 32) {
            const float* Wsl = e.W + (size_t)o0 * 2 * e.C;
            dim3 gym(NP, B_SZ);
            if (e.C == 3)       k_ymk<3><<<gym, 256, 0, stream>>>(e.x, e.rs, Wsl, sti, ybuf);
            else if (e.C == 64) k_ymk<64><<<gym, 256, 0, stream>>>(e.x, e.rs, Wsl, sti, ybuf);
            else                k_ymk<128><<<gym, 256, 0, stream>>>(e.x, e.rs, Wsl, sti, ybuf);
            k_pwsum<<<1024, 256, 0, stream>>>(ybuf, nullptr, 0, psum2m);
            k_pwsum<<<1024, 256, 0, stream>>>(ybuf, psum2m, 1, psum2v);
            k_xwrite<<<2048, 256, 0, stream>>>(ybuf, psum2m, psum2v,
                                               e.g + o0, e.bb + o0, e.coff + o0, loc);
        }
    }

    auto gemm = [&](const float* X, int rsX, const float* Wp, int rsW, int K, int O,
                    float* o_, int rsO, const float* aux, long long bsA, int mode) {
        dim3 g(NP / 128, (O + 127) / 128, B_SZ);
        enc_gemm<<<g, 256, 0, stream>>>(X, (long long)NP * rsX, rsX, Wp, rsW, K, O,
                                        o_, (long long)NP * rsO, rsO, aux, bsA, mode);
    };

    // stage C
    gemm(loc, 512, W5, 512, 512, 256, y5, 256, nullptr, 0, 0);
    enc_gn5<<<dim3(32, B_SZ), 256, 0, stream>>>(y5, g5, b5, glb);
    enc_t1<<<dim3(4, B_SZ), 128, 0, stream>>>(Wm1, bm1, glb, t1);

    // stage D
    gemm(loc, 512, Wm1, 1024, 512, 512, z1, 512, t1, 512, 1);
    enc_gnstats<<<dim3(32, B_SZ), 256, 0, stream>>>(z1, 512, 4, gm, gr);
    enc_gnapply<<<(B_SZ * NP * 512) / 256, 256, 0, stream>>>(z1, 512, 4, 20, gm1, hm1, gm, gr);

    gemm(z1, 512, Wm2, 512, 512, 256, z2, 256, bm2, 0, 1);
    enc_gnstats<<<dim3(32, B_SZ), 256, 0, stream>>>(z2, 256, 3, gm, gr);
    enc_gnapply<<<(B_SZ * NP * 256) / 256, 256, 0, stream>>>(z2, 256, 3, 19, gm2, hm2, gm, gr);

    gemm(z2, 256, Wm3, 256, 256, 128, emb, 128, bm3, 0, 1);
    enc_gnstats<<<dim3(32, B_SZ), 256, 0, stream>>>(emb, 128, 2, gm, gr);
    enc_gnapply<<<(B_SZ * NP * 128) / 256, 256, 0, stream>>>(emb, 128, 2, 18, gm3, hm3, gm, gr);

    enc_out<<<dim3(64, 4, B_SZ), dim3(32, 8), 0, stream>>>(emb, out);
    enc_outglb<<<16, 256, 0, stream>>>(glb, out);
}